// Round 10
// baseline (85.158 us; speedup 1.0000x reference)
//
#include <hip/hip_runtime.h>
#include <stdint.h>

typedef float  float4v  __attribute__((ext_vector_type(4)));
typedef long long llong2v __attribute__((ext_vector_type(2)));
typedef int    int8v   __attribute__((ext_vector_type(8)));
typedef unsigned int uint4v __attribute__((ext_vector_type(4)));

// Problem constants (N=8192, n_in=256, m=256, k=8)
// GEMM: [8192 x 512] x [512 x 8192] fp8 e4m3 via MX-scale MFMA (K=128, scale=1.0),
// fused LSTM epilogue. W pre-scaled by 16 in fp8; undone in epilogue.
// A  layout: [rb 128][kt 8][4KB]  (kt slot = [rf 4][gq 4][lane 16][16B])
// Bt layout: [cb 32][kt 8][16KB]  (kt slot = [q 4][wn 4][gq 4][lane 16][16B])
// Byte b of granule gq = orig within-kt k = (b>>3)*32 + gq*8 + (b&7), SAME for A
// and B -> any K-permutation applied to both sides is MFMA-correct.
// Tile 64x256, 8 waves = 2M x 4N, acc 32 f32/lane -> 2 blocks/CU.

__device__ __forceinline__ unsigned int pk4fp8(float a, float b, float c, float d) {
  unsigned int p = (unsigned int)__builtin_amdgcn_cvt_pk_fp8_f32(a, b, 0, false);
  p = (unsigned int)__builtin_amdgcn_cvt_pk_fp8_f32(c, d, (int)p, true);
  return p;
}

__device__ __forceinline__ float sigm(float x) {
  return __builtin_amdgcn_rcpf(1.0f + __expf(-x));
}
__device__ __forceinline__ float tanh_(float x) {
  return fmaf(2.0f, __builtin_amdgcn_rcpf(1.0f + __expf(-2.0f * x)), -1.0f);
}

__device__ __forceinline__ void gll16(const void* g, void* l) {
  __builtin_amdgcn_global_load_lds((const __attribute__((address_space(1))) void*)g,
                                   (__attribute__((address_space(3))) void*)l, 16, 0, 0);
}

#define BARRIER   asm volatile("s_barrier" ::: "memory")
#define WAITLGKM  asm volatile("s_waitcnt lgkmcnt(0)" ::: "memory")
#define WAITVM0   asm volatile("s_waitcnt vmcnt(0)" ::: "memory")
#define PRIO1     __builtin_amdgcn_s_setprio(1)
#define PRIO0     __builtin_amdgcn_s_setprio(0)

// ------------- P: merged prep. blocks 0..2047 = A+logits ; 2048..3071 = Bt --------
__global__ void prep_all(const float* __restrict__ x, const float* __restrict__ h,
                         const float* __restrict__ u, const float* __restrict__ Wxz,
                         const float* __restrict__ Whz, const float* __restrict__ bxz,
                         const void* __restrict__ taup,
                         const float* __restrict__ Wx, const float* __restrict__ Wh,
                         uint8_t* __restrict__ A, uint8_t* __restrict__ Bt,
                         float* __restrict__ z_out, float* __restrict__ qz_out) {
  __shared__ float tile[64][64];

  if (blockIdx.x < 2048) {
    // ---------------- A conversion + logits ----------------
    int lane = threadIdx.x & 63;
    int n = blockIdx.x * 4 + (threadIdx.x >> 6);
    float4v xv = *(const float4v*)(x + (size_t)n * 256 + lane * 4);
    float4v hv = *(const float4v*)(h + (size_t)n * 256 + lane * 4);

    // fp8 A write: lane i covers orig k = 4i..4i+3 (x) and 256+4i.. (h)
    {
      unsigned int px = pk4fp8(xv[0], xv[1], xv[2], xv[3]);
      unsigned int ph = pk4fp8(hv[0], hv[1], hv[2], hv[3]);
      int r = n & 63;
      int gq  = (lane >> 1) & 3;
      int sub = ((lane >> 3) & 1) * 8 + (lane & 1) * 4;
      uint8_t* base = A + (size_t)(n >> 6) * 32768
                    + ((r >> 4) << 10) + (gq << 8) + ((r & 15) << 4) + sub;
      int ktx = lane >> 4;
      *(unsigned int*)(base + ktx * 4096) = px;
      *(unsigned int*)(base + (4 + ktx) * 4096) = ph;
    }

    float p[8];
#pragma unroll
    for (int j = 0; j < 8; ++j) p[j] = 0.0f;
#pragma unroll
    for (int ii = 0; ii < 4; ++ii) {
      int i = lane * 4 + ii;
      float xs = xv[ii], hs = hv[ii];
#pragma unroll
      for (int j = 0; j < 8; ++j)
        p[j] += xs * Wxz[i * 8 + j] + hs * Whz[i * 8 + j];
    }
#pragma unroll
    for (int j = 0; j < 8; ++j)
      for (int off = 32; off > 0; off >>= 1) p[j] += __shfl_down(p[j], off, 64);

    if (lane == 0) {
      int   iv = ((const int*)taup)[0];
      float fv = ((const float*)taup)[0];
      float tau = (iv >= 1 && iv < 100000) ? (float)iv : fv;
      float tinv = 1.0f / tau;

      float logit[8], e[8];
      float mx = -1e30f;
#pragma unroll
      for (int j = 0; j < 8; ++j) { logit[j] = p[j] + bxz[j]; mx = fmaxf(mx, logit[j]); }
      float s = 0.0f;
#pragma unroll
      for (int j = 0; j < 8; ++j) { e[j] = __expf(logit[j] - mx); s += e[j]; }
      float inv = 1.0f / s;
#pragma unroll
      for (int j = 0; j < 8; ++j) qz_out[(size_t)n * 8 + j] = e[j] * inv;

      float t[8];
      float mt = -1e30f;
#pragma unroll
      for (int j = 0; j < 8; ++j) {
        float uu = u[(size_t)n * 8 + j];
        float g = -__logf(-__logf(uu + 1e-10f) + 1e-10f);
        t[j] = (logit[j] + g) * tinv;
        mt = fmaxf(mt, t[j]);
      }
      float s2 = 0.0f;
#pragma unroll
      for (int j = 0; j < 8; ++j) { e[j] = __expf(t[j] - mt); s2 += e[j]; }
      float inv2 = 1.0f / s2;
#pragma unroll
      for (int j = 0; j < 8; ++j) z_out[(size_t)n * 8 + j] = e[j] * inv2;
    }
    return;
  }

  // ---------------- Bt conversion ----------------
  // p(C) = (mm>>3)*256 + (g>>1)*128 + (g&1)*64 + (kk>>1)*16 + (kk&1)*8 + (mm&7)
  int bid = blockIdx.x - 2048;
  int tid = threadIdx.x;
  int wi = bid & 7;            // 64-k window == kt
  int C0 = (bid >> 3) << 6;    // 64-col group
#pragma unroll
  for (int qq = 0; qq < 4; ++qq) {
    int flat = qq * 256 + tid;        // 1024 float4 = 64 x 64
    int rr = flat >> 4, c4 = (flat & 15) << 2;
    int ig = wi * 64 + rr;
    const float* src = (ig < 256) ? (Wx + (size_t)ig * 8192 + C0 + c4)
                                  : (Wh + (size_t)(ig - 256) * 8192 + C0 + c4);
    float4v v = *(const float4v*)src;
    float4v w;
#pragma unroll
    for (int e = 0; e < 4; ++e) w[e] = v[e] * 16.0f;
    *(float4v*)&tile[rr][c4] = w;
  }
  __syncthreads();
  int c = tid & 63, gq = tid >> 6;
  int C = C0 + c;
  int g = C >> 11, kk = (C >> 8) & 7, mm = C & 255;
  int p = ((mm >> 3) << 8) | ((g >> 1) << 7) | ((g & 1) << 6)
        | ((kk >> 1) << 4) | ((kk & 1) << 3) | (mm & 7);
  uint4v o;
  o[0] = pk4fp8(tile[gq * 8 + 0][c], tile[gq * 8 + 1][c], tile[gq * 8 + 2][c], tile[gq * 8 + 3][c]);
  o[1] = pk4fp8(tile[gq * 8 + 4][c], tile[gq * 8 + 5][c], tile[gq * 8 + 6][c], tile[gq * 8 + 7][c]);
  o[2] = pk4fp8(tile[32 + gq * 8 + 0][c], tile[32 + gq * 8 + 1][c], tile[32 + gq * 8 + 2][c], tile[32 + gq * 8 + 3][c]);
  o[3] = pk4fp8(tile[32 + gq * 8 + 4][c], tile[32 + gq * 8 + 5][c], tile[32 + gq * 8 + 6][c], tile[32 + gq * 8 + 7][c]);
  int cl = p & 255;   // q=cl>>6, wn=(cl>>4)&3, lane=cl&15
  int off = ((cl >> 6) << 12) + (((cl >> 4) & 3) << 10) + (gq << 8) + ((cl & 15) << 4);
  *(uint4v*)(Bt + (size_t)(p >> 8) * 131072 + wi * 16384 + off) = o;
}

// ---------------- G: fp8-MX 64x256-tile GEMM + fused LSTM epilogue ----------------
// 8 waves = 2M(wm) x 4N(wn). Per wave: 32 rows (wm*32 + j*16 + gl*4 + r),
// lane cols = 4 gate-quadrants q of one (kk,mm): kk = wn*2+(ml>>3), mml = ml&7.
// acc[q][j]: 8 float4v = 32 f32/lane. K consumed 128/iter via mfma_scale.
__global__ __launch_bounds__(512, 4) void gates_kernel(
    const uint8_t* __restrict__ A,    // [rb 128][kt 8][4KB] fp8
    const uint8_t* __restrict__ Bt,   // [cb 32][kt 8][16KB] fp8
    const float* __restrict__ c0g,    // [8192][256]
    const float* __restrict__ bias,   // [8192]
    const float* __restrict__ zg,     // [8192][8]
    float* __restrict__ h_out, float* __restrict__ c_out) {
  __shared__ char smem[40960];  // A: 2 x 4KB @0 ; B: 2 x 16KB @8192

  const int tid = threadIdx.x;
  const int lane = tid & 63, ml = lane & 15, gl = lane >> 4;
  const int wid = tid >> 6, wm = wid >> 2, wn = wid & 3;

  // XCD-stripe: xcd owns rb {16x..16x+15}, cb outer / rb inner.
  const int xcd = blockIdx.x & 7;
  const int j_  = blockIdx.x >> 3;          // 0..511
  const int cb  = j_ >> 4;                  // 0..31
  const int rb  = (xcd << 4) | (j_ & 15);   // 0..127
  const int row0 = rb << 6;

  const uint8_t* Abp = A + (size_t)rb * 32768;
  const uint8_t* Bbp = Bt + (size_t)cb * 131072;

  // fragment LDS bases — quarter-wave-contiguous (gq*256 + ml*16)
  const char* pa = smem + (wm << 11) + (gl << 8) + (ml << 4);           // + j*1024, + slot*4096
  const char* pb = smem + 8192 + (wn << 10) + (gl << 8) + (ml << 4);    // + q*4096, + slot*16384

  // stage double-kt T (kts 2T,2T+1): A 8KB + B 32KB, fully linear
#define STG(T) do { \
    gll16(Abp + (T) * 8192 + (tid << 4), smem + (tid << 4)); \
    _Pragma("unroll") for (int s_ = 0; s_ < 4; ++s_) \
      gll16(Bbp + (T) * 32768 + s_ * 8192 + (tid << 4), \
            smem + 8192 + s_ * 8192 + (tid << 4)); \
  } while (0)

  union frag { int8v v; llong2v h[2]; };
  frag af[2], bf[4];

#define RDALL() { \
    _Pragma("unroll") for (int j = 0; j < 2; ++j) \
      _Pragma("unroll") for (int s_ = 0; s_ < 2; ++s_) \
        af[j].h[s_] = *(const llong2v*)(pa + s_ * 4096 + j * 1024); \
    _Pragma("unroll") for (int q = 0; q < 4; ++q) \
      _Pragma("unroll") for (int s_ = 0; s_ < 2; ++s_) \
        bf[q].h[s_] = *(const llong2v*)(pb + s_ * 16384 + q * 4096); }

#define MMALL() { _Pragma("unroll") for (int j = 0; j < 2; ++j) \
    _Pragma("unroll") for (int q = 0; q < 4; ++q) \
      acc[q][j] = __builtin_amdgcn_mfma_scale_f32_16x16x128_f8f6f4( \
          af[j].v, bf[q].v, acc[q][j], 0, 0, 0, 0x7F7F7F7F, 0, 0x7F7F7F7F); }

  float4v acc[4][2];   // [gate q][row frag j]
#pragma unroll
  for (int q = 0; q < 4; ++q)
#pragma unroll
    for (int j = 0; j < 2; ++j)
#pragma unroll
      for (int r = 0; r < 4; ++r) acc[q][j][r] = 0.0f;

  // prologue: stage double-kt 0
  STG(0);
  WAITVM0;
  BARRIER;

#pragma unroll
  for (int t = 0; t < 4; ++t) {
    RDALL();                       // 12 x ds_read_b128 -> 48 VGPR
    WAITLGKM;                      // reads landed (required before overwrite)
    BARRIER;                       // ALL waves done reading slots
    if (t < 3) STG(t + 1);         // issue next 40KB while MFMA runs
    PRIO1; MMALL(); PRIO0;         // 8 x mfma_scale 16x16x128
    if (t < 3) { WAITVM0; }
    BARRIER;                       // staged data visible to all
  }
#undef STG
#undef RDALL
#undef MMALL

  // ---------------- fused LSTM epilogue ----------------
  const int kkl = (wn << 1) | (ml >> 3);
  const int mml = ml & 7;
  {
    const int mmg = (cb << 3) + mml;
    const float bI = bias[0 * 2048 + kkl * 256 + mmg];
    const float bG = bias[1 * 2048 + kkl * 256 + mmg];
    const float bF = bias[2 * 2048 + kkl * 256 + mmg];
    const float bO = bias[3 * 2048 + kkl * 256 + mmg];
    const float s16 = 0.0625f;   // undo W*16 pre-scale

    float hpart[2][4], cpart[2][4];
#pragma unroll
    for (int j = 0; j < 2; ++j) {
      const int nb = row0 + (wm << 5) + (j << 4) + (gl << 2);
#pragma unroll
      for (int r = 0; r < 4; ++r) {
        const int nrow = nb + r;
        float I = fmaf(acc[0][j][r], s16, bI);
        float G = fmaf(acc[1][j][r], s16, bG);
        float F = fmaf(acc[2][j][r], s16, bF);
        float O = fmaf(acc[3][j][r], s16, bO);
        float c0v = c0g[(size_t)nrow * 256 + mmg];
        float ct = fmaf(sigm(F), c0v, sigm(I) * tanh_(G));
        float ht = sigm(O) * tanh_(ct);
        float zv = zg[(size_t)nrow * 8 + kkl];
        float h1 = zv * ht, c1 = zv * ct;
        h1 += __shfl_xor(h1, 8, 64);    // combine the wave's kk pair
        c1 += __shfl_xor(c1, 8, 64);
        hpart[j][r] = h1;
        cpart[j][r] = c1;
      }
    }

    // pbuf [wn 4][row 64][16] : cols 0..7 = h, 8..15 = c (16KB, reuses B region)
    float* pbuf = (float*)(smem + 8192);
    const bool wr = ((ml & 8) == 0);
    if (wr) {
#pragma unroll
      for (int j = 0; j < 2; ++j)
#pragma unroll
        for (int r = 0; r < 4; ++r) {
          int rloc = (wm << 5) + (j << 4) + (gl << 2) + r;
          pbuf[(wn << 10) + (rloc << 4) + mml]     = hpart[j][r];
          pbuf[(wn << 10) + (rloc << 4) + 8 + mml] = cpart[j][r];
        }
    }
    WAITLGKM; BARRIER;
    // reduce over wn and store: 64 rows x (8 h + 8 c) = 1024 values, 2/thread
#pragma unroll
    for (int i = 0; i < 2; ++i) {
      int idx = (i << 9) + tid;          // 0..1023
      int rloc = idx >> 4, cc = idx & 15;
      float v = pbuf[(rloc << 4) + cc]
              + pbuf[1024 + (rloc << 4) + cc]
              + pbuf[2048 + (rloc << 4) + cc]
              + pbuf[3072 + (rloc << 4) + cc];
      float* dst = (cc < 8) ? h_out : c_out;
      dst[(size_t)(row0 + rloc) * 256 + (cb << 3) + (cc & 7)] = v;
    }
  }
}

extern "C" void kernel_launch(void* const* d_in, const int* in_sizes, int n_in,
                              void* d_out, int out_size, void* d_ws, size_t ws_size,
                              hipStream_t stream) {
  const float* x   = (const float*)d_in[0];
  const float* h0  = (const float*)d_in[1];
  const float* c0  = (const float*)d_in[2];
  const float* u   = (const float*)d_in[3];
  const float* Wxz = (const float*)d_in[4];
  const float* Whz = (const float*)d_in[5];
  const float* Wx4 = (const float*)d_in[6];
  const float* Wh4 = (const float*)d_in[7];
  const float* bxz = (const float*)d_in[8];
  const float* b4  = (const float*)d_in[9];
  const void*  tau = d_in[10];

  float* out    = (float*)d_out;
  float* z_out  = out;                       // [8192][8]
  float* qz_out = out + 65536;               // [8192][8]
  float* h_out  = out + 131072;              // [8192][256]
  float* c_out  = out + 131072 + 2097152;    // [8192][256]

  uint8_t* A  = (uint8_t*)d_ws;              // 4MB fp8
  uint8_t* Bt = A + 4194304;                 // 4MB fp8

  prep_all<<<3072, 256, 0, stream>>>(x, h0, u, Wxz, Whz, bxz, tau,
                                     Wx4, Wh4, A, Bt, z_out, qz_out);
  gates_kernel<<<4096, 512, 0, stream>>>(A, Bt, c0, b4, z_out, h_out, c_out);
}